// Round 1
// 666.996 us; speedup vs baseline: 1.0727x; 1.0727x over previous
//
#include <hip/hip_runtime.h>
#include <math.h>

#define T_IN    480000
#define NFRAMES 1876
#define NF      513      // 1024/2 + 1
#define NFFT    1024
#define HOPSZ   256
#define NBATCH  16
#define SSTR    516      // staged f-stride, multiple of 4 so float4 rows stay 16B-aligned
#define TT      128      // transpose tile width along t

// LDS bank-conflict-avoidance map: +1 float pad every 16
#define MAP(i) ((i) + ((i) >> 4))

__device__ __forceinline__ int reflect_idx(int q) {
    if (q < 0) q = -q;
    if (q >= T_IN) q = 2 * T_IN - 2 - q;
    return q;
}

// base-4 digit reversal of a 10-bit index = 10-bit bit reversal, then swap bit pairs
__device__ __forceinline__ int digitrev4_10(int f) {
    unsigned r = __brev((unsigned)f) >> 22;
    return (int)(((r & 0x155u) << 1) | ((r & 0x2AAu) >> 1));
}

// Branchless atan2 via v_rcp + odd minimax poly on [0,1]; max err ~1e-5 rad.
// Replaces libm atan2f (~35 instrs w/ precise div) with ~16 instrs.
__device__ __forceinline__ float fast_atan2f(float y, float x) {
    float ax = fabsf(x), ay = fabsf(y);
    float mx = fmaxf(ax, ay);
    float mn = fminf(ax, ay);
    float r  = mn * __builtin_amdgcn_rcpf(fmaxf(mx, 1e-30f));
    float s  = r * r;
    float p  = -0.0117212f;
    p = fmaf(p, s,  0.05265332f);
    p = fmaf(p, s, -0.11643287f);
    p = fmaf(p, s,  0.19354346f);
    p = fmaf(p, s, -0.33262347f);
    p = fmaf(p, s,  0.99997726f);
    float a = r * p;
    a = (ay > ax)   ? (1.57079632679489662f - a) : a;
    a = (x < 0.0f)  ? (3.14159265358979324f - a) : a;
    return copysignf(a, y);
}

// One block (256 threads) = one STFT frame; computes all 6 channels.
// DIRECT=0: staged layout ws[((b*T'+t)*6+c)*SSTR + f]   (coalesced in f)
// DIRECT=1: final layout  out[((b*6+c)*NF+f)*T' + t]    (uncoalesced fallback)
template <int DIRECT>
__global__ __launch_bounds__(256)
void w2t_frame_kernel(const float* __restrict__ x, float* __restrict__ dst) {
    __shared__ float sre[1088];    // 1024 + pad
    __shared__ float sim[1088];
    __shared__ float twc[512];     // W_1024^j = exp(-2pi i j/1024), j<512
    __shared__ float tws[512];
    __shared__ float smag[NF];
    __shared__ float sdb[NF];
    __shared__ float sdown[657];   // k=2:256 | k=3:171 | k=4:128 | k=5:102

    const int blk = blockIdx.x;
    const int b   = blk / NFRAMES;
    const int t   = blk - b * NFRAMES;
    const int tid = threadIdx.x;

    const float* xl = x + (size_t)(b * 2 + 0) * T_IN;
    const float* xr = x + (size_t)(b * 2 + 1) * T_IN;

    // ---- twiddle table: 2 sincos per thread (vs per-butterfly sincos) ----
    for (int j = tid; j < 512; j += 256) {
        float sn, cs;
        __sincosf(-6.28318530717958648f * (float)j * (1.0f / 1024.0f), &sn, &cs);
        twc[j] = cs; tws[j] = sn;
    }

    // ---- natural-order load + Hann window (stereo packed as complex) ----
#pragma unroll
    for (int i = 0; i < 4; i++) {
        int n = tid + i * 256;
        int q = reflect_idx(t * HOPSZ + n - NFFT / 2);
        float w = 0.5f - 0.5f * __cosf(6.28318530717958648f * (float)n * (1.0f / 1024.0f));
        sre[MAP(n)] = xl[q] * w;
        sim[MAP(n)] = xr[q] * w;
    }

    // ---- 1024-pt complex FFT: radix-4 DIF, in-place, digit-reversed output ----
#pragma unroll
    for (int r = 0; r < 5; r++) {
        __syncthreads();
        const int lq = 8 - 2 * r;        // q = 256,64,16,4,1
        const int q  = 1 << lq;
        int n = tid & (q - 1);
        int g = tid >> lq;
        int base = (g << (lq + 2)) + n;
        int i0 = MAP(base);
        int i1 = MAP(base + q);
        int i2 = MAP(base + 2 * q);
        int i3 = MAP(base + 3 * q);
        float ar = sre[i0], ai = sim[i0];
        float br = sre[i1], bi = sim[i1];
        float cr = sre[i2], ci = sim[i2];
        float dr = sre[i3], di = sim[i3];
        float t0r = ar + cr, t0i = ai + ci;
        float t1r = ar - cr, t1i = ai - ci;
        float t2r = br + dr, t2i = bi + di;
        float t3r = br - dr, t3i = bi - di;
        float u0r = t0r + t2r, u0i = t0i + t2i;
        float v2r = t0r - t2r, v2i = t0i - t2i;
        float v1r = t1r + t3i, v1i = t1i - t3r;   // t1 - i*t3
        float v3r = t1r - t3i, v3i = t1i + t3r;   // t1 + i*t3
        int j1 = n << (2 * r);                    // W_{Nr}^n = W_1024^{n<<2r}
        int j2 = j1 + j1;
        float w1c = twc[j1], w1s = tws[j1];
        float w2c = twc[j2], w2s = tws[j2];
        float w3c = w1c * w2c - w1s * w2s;        // W^{3n} = W^n * W^{2n}
        float w3s = w1c * w2s + w1s * w2c;
        sre[i0] = u0r;                       sim[i0] = u0i;
        sre[i1] = v1r * w1c - v1i * w1s;     sim[i1] = v1r * w1s + v1i * w1c;
        sre[i2] = v2r * w2c - v2i * w2s;     sim[i2] = v2r * w2s + v2i * w2c;
        sre[i3] = v3r * w3c - v3i * w3s;     sim[i3] = v3r * w3s + v3i * w3c;
    }
    __syncthreads();

    const size_t frame_base = (size_t)(b * NFRAMES + t) * 6 * SSTR;
    auto store = [&](int c, int f, float v) {
        if (DIRECT)
            dst[(((size_t)(b * 6 + c)) * NF + f) * NFRAMES + t] = v;
        else
            dst[frame_base + (size_t)c * SSTR + f] = v;
    };

    // ---- unpack L/R spectra (digit-reversed positions), per-bin channels ----
    for (int f = tid; f < NF; f += 256) {
        int pa = MAP(digitrev4_10(f));
        int pb = MAP(digitrev4_10((NFFT - f) & (NFFT - 1)));
        float Ar = sre[pa], Ai = sim[pa];
        float Br = sre[pb], Bi = sim[pb];
        float Lre = 0.5f * (Ar + Br), Lim = 0.5f * (Ai - Bi);
        float Rre = 0.5f * (Ai + Bi), Rim = 0.5f * (Br - Ar);
        float spr = 0.5f * (Lre + Rre), spi = 0.5f * (Lim + Rim);
        float m = __builtin_amdgcn_sqrtf(spr * spr + spi * spi);   // v_sqrt_f32
        smag[f] = m;
        // 20*log10(z) = 20*log10(2) * log2(z); v_log_f32 is log2
        sdb[f]  = 6.02059991327962390f * __builtin_amdgcn_logf(m + 1e-10f);
        float ipd = fast_atan2f(Lim, Lre) - fast_atan2f(Rim, Rre);
        float le  = Lre * Lre + Lim * Lim;
        float ren = Rre * Rre + Rim * Rim;
        float pan = (le - ren) * __builtin_amdgcn_rcpf(le + ren + 1e-10f);
        store(0, f, spr);
        store(1, f, spi);
        store(3, f, ipd);
        store(4, f, pan);
    }
    __syncthreads();

    // ---- HPS downsampled arrays (jax.image.resize linear, half-pixel, clamped) ----
    for (int j = tid; j < 657; j += 256) {
        int jj, fd;
        if (j < 256)      { jj = j;       fd = 256; }
        else if (j < 427) { jj = j - 256; fd = 171; }
        else if (j < 555) { jj = j - 427; fd = 128; }
        else              { jj = j - 555; fd = 102; }
        float scale = 513.0f / (float)fd;
        float xc = ((float)jj + 0.5f) * scale - 0.5f;
        float fl = floorf(xc);
        float w  = xc - fl;
        int i0 = (int)fl;
        int c0 = min(max(i0, 0), NF - 1);
        int c1 = min(max(i0 + 1, 0), NF - 1);
        sdown[j] = (1.0f - w) * smag[c0] + w * smag[c1];
    }
    __syncthreads();

    // ---- harmonic product + psychoacoustic spreading ----
    // Gaussian taps |d|>=6 weigh <= 6.1e-9 -> truncated (abs err < 2.5e-6 on ch5)
    const float SW[21] = {
        7.6945986e-23f, 1.0279774e-18f, 5.0522711e-15f, 9.1347204e-12f,
        6.0758829e-09f, 1.4867195e-06f, 1.3383023e-04f, 4.4318484e-03f,
        5.3990967e-02f, 2.4197072e-01f, 3.9894228e-01f, 2.4197072e-01f,
        5.3990967e-02f, 4.4318484e-03f, 1.3383023e-04f, 1.4867195e-06f,
        6.0758829e-09f, 9.1347204e-12f, 5.0522711e-15f, 1.0279774e-18f,
        7.6945986e-23f };
    const int offs[4] = { 0, 256, 427, 555 };
    const int fds[4]  = { 256, 171, 128, 102 };

    for (int f = tid; f < NF; f += 256) {
        float h = smag[f];
#pragma unroll
        for (int q = 0; q < 4; q++) {
            float scale = (float)fds[q] * (1.0f / 513.0f);
            float xc = ((float)f + 0.5f) * scale - 0.5f;
            float fl = floorf(xc);
            float w  = xc - fl;
            int i0 = (int)fl;
            int c0 = min(max(i0, 0), fds[q] - 1);
            int c1 = min(max(i0 + 1, 0), fds[q] - 1);
            h *= (1.0f - w) * sdown[offs[q] + c0] + w * sdown[offs[q] + c1];
        }
        store(2, f, h);

        float acc = 0.0f;
#pragma unroll
        for (int d = -5; d <= 5; d++) {
            int ff = f + d;
            if (ff >= 0 && ff < NF) acc += SW[d + 10] * sdb[ff];
        }
        store(5, f, acc - 20.0f);
    }
}

// (b,t,c,f) staged -> (b,c,f,t) final; 64(f) x 128(t) tiles, float4 both directions
__global__ __launch_bounds__(256)
void w2t_transpose_kernel(const float* __restrict__ ws, float* __restrict__ out) {
    __shared__ float tile[64][TT + 4];   // [f_local][t_local], row stride 132 (16B-aligned)
    const int bc = blockIdx.z;           // b*6 + c
    const int b  = bc / 6;
    const int c  = bc - b * 6;
    const int f0 = blockIdx.x * 64;
    const int t0 = blockIdx.y * TT;
    const int u  = threadIdx.x;

    // load: rows = t (16 per pass, 8 passes), float4 along f
    {
        const int txq = u & 15;          // f quad index
        const int ty  = u >> 4;          // 0..15
#pragma unroll
        for (int i = 0; i < 8; i++) {
            int tl = ty + 16 * i;
            int tt = t0 + tl;
            if (tt < NFRAMES) {
                const float* row = ws + ((size_t)((size_t)b * NFRAMES + tt) * 6 + c) * SSTR + f0;
                int fb = txq * 4;
                if (f0 + fb + 3 < NF) {
                    float4 v = *(const float4*)(row + fb);
                    tile[fb + 0][tl] = v.x;
                    tile[fb + 1][tl] = v.y;
                    tile[fb + 2][tl] = v.z;
                    tile[fb + 3][tl] = v.w;
                } else {
#pragma unroll
                    for (int j = 0; j < 4; j++)
                        if (f0 + fb + j < NF) tile[fb + j][tl] = row[fb + j];
                }
            }
        }
    }
    __syncthreads();

    // store: rows = f (8 per pass, 8 passes), float4 along t (512B segments per wave-row)
    {
        const int tq = u & 31;           // t quad index
        const int fy = u >> 5;           // 0..7
#pragma unroll
        for (int i = 0; i < 8; i++) {
            int fl = fy + 8 * i;
            int ff = f0 + fl;
            if (ff < NF) {
                float* orow = out + ((size_t)bc * NF + ff) * NFRAMES + t0;
                int tb = tq * 4;
                if (t0 + tb + 3 < NFRAMES) {
                    float4 v;
                    v.x = tile[fl][tb + 0];
                    v.y = tile[fl][tb + 1];
                    v.z = tile[fl][tb + 2];
                    v.w = tile[fl][tb + 3];
                    *(float4*)(orow + tb) = v;
                } else {
#pragma unroll
                    for (int j = 0; j < 4; j++)
                        if (t0 + tb + j < NFRAMES) orow[tb + j] = tile[fl][tb + j];
                }
            }
        }
    }
}

extern "C" void kernel_launch(void* const* d_in, const int* in_sizes, int n_in,
                              void* d_out, int out_size, void* d_ws, size_t ws_size,
                              hipStream_t stream) {
    const float* x = (const float*)d_in[0];
    float* out = (float*)d_out;

    const size_t staged_bytes = (size_t)NBATCH * NFRAMES * 6 * SSTR * sizeof(float);
    dim3 g1(NBATCH * NFRAMES);

    if (ws_size >= staged_bytes) {
        float* ws = (float*)d_ws;
        hipLaunchKernelGGL((w2t_frame_kernel<0>), g1, dim3(256), 0, stream, x, ws);
        dim3 g2((NF + 63) / 64, (NFRAMES + TT - 1) / TT, NBATCH * 6);
        hipLaunchKernelGGL(w2t_transpose_kernel, g2, dim3(256), 0, stream, ws, out);
    } else {
        hipLaunchKernelGGL((w2t_frame_kernel<1>), g1, dim3(256), 0, stream, x, out);
    }
}

// Round 2
// 653.133 us; speedup vs baseline: 1.0955x; 1.0212x over previous
//
#include <hip/hip_runtime.h>
#include <math.h>

#define T_IN    480000
#define NFRAMES 1876
#define NF      513      // 1024/2 + 1
#define NFFT    1024
#define HOPSZ   256
#define NBATCH  16
#define SSTR    516      // staged f-stride, multiple of 4 so float4 rows stay 16B-aligned
#define TT      128      // transpose tile width along t

// LDS pad map: +4 floats every 32 -> keeps 16B alignment and 4-contiguity for b128,
// conflict-free (or <=2-way, which is free) for all FFT round strides.
#define MAP(i) ((i) + ((((i) >> 5)) << 2))

__device__ __forceinline__ int reflect_idx(int q) {
    if (q < 0) q = -q;
    if (q >= T_IN) q = 2 * T_IN - 2 - q;
    return q;
}

// base-4 digit reversal of a 10-bit index = 10-bit bit reversal, then swap bit pairs
__device__ __forceinline__ int digitrev4_10(int f) {
    unsigned r = __brev((unsigned)f) >> 22;
    return (int)(((r & 0x155u) << 1) | ((r & 0x2AAu) >> 1));
}

// Branchless atan2 via v_rcp + odd minimax poly on [0,1]; max err ~1e-5 rad.
__device__ __forceinline__ float fast_atan2f(float y, float x) {
    float ax = fabsf(x), ay = fabsf(y);
    float mx = fmaxf(ax, ay);
    float mn = fminf(ax, ay);
    float r  = mn * __builtin_amdgcn_rcpf(fmaxf(mx, 1e-30f));
    float s  = r * r;
    float p  = -0.0117212f;
    p = fmaf(p, s,  0.05265332f);
    p = fmaf(p, s, -0.11643287f);
    p = fmaf(p, s,  0.19354346f);
    p = fmaf(p, s, -0.33262347f);
    p = fmaf(p, s,  0.99997726f);
    float a = r * p;
    a = (ay > ax)   ? (1.57079632679489662f - a) : a;
    a = (x < 0.0f)  ? (3.14159265358979324f - a) : a;
    return copysignf(a, y);
}

// One block (256 threads) = one STFT frame; computes all 6 channels.
// DIRECT=0: staged layout ws[((b*T'+t)*6+c)*SSTR + f]   (coalesced in f)
// DIRECT=1: final layout  out[((b*6+c)*NF+f)*T' + t]    (uncoalesced fallback)
template <int DIRECT>
__global__ __launch_bounds__(256)
void w2t_frame_kernel(const float* __restrict__ x, float* __restrict__ dst) {
    __shared__ float sre[1152];    // 1024 + 4-per-32 pad
    __shared__ float sim[1152];
    __shared__ float smag[NF];
    __shared__ float sdb[NF];
    __shared__ float sdown[657];   // k=2:256 | k=3:171 | k=4:128 | k=5:102

    const int blk = blockIdx.x;
    const int b   = blk / NFRAMES;
    const int t   = blk - b * NFRAMES;
    const int tid = threadIdx.x;

    const float* xl = x + (size_t)(b * 2 + 0) * T_IN;
    const float* xr = x + (size_t)(b * 2 + 1) * T_IN;

    // ---- natural-order load + Hann window (stereo packed as complex) ----
    if (t >= 2 && t <= NFRAMES - 3) {
        // interior: indices t*256-512 .. t*256+511 all in [0, T_IN) and 16B-aligned
        const float4* xl4 = (const float4*)(xl + t * HOPSZ - NFFT / 2);
        const float4* xr4 = (const float4*)(xr + t * HOPSZ - NFFT / 2);
        float4 vl = xl4[tid];
        float4 vr = xr4[tid];
        int n0 = tid << 2;
        float w0 = 0.5f - 0.5f * __cosf(6.28318530717958648f * (float)(n0 + 0) * (1.0f / 1024.0f));
        float w1 = 0.5f - 0.5f * __cosf(6.28318530717958648f * (float)(n0 + 1) * (1.0f / 1024.0f));
        float w2 = 0.5f - 0.5f * __cosf(6.28318530717958648f * (float)(n0 + 2) * (1.0f / 1024.0f));
        float w3 = 0.5f - 0.5f * __cosf(6.28318530717958648f * (float)(n0 + 3) * (1.0f / 1024.0f));
        int m = MAP(n0);                               // 4-aligned, contiguous within 32-block
        float4 wre = { vl.x * w0, vl.y * w1, vl.z * w2, vl.w * w3 };
        float4 wim = { vr.x * w0, vr.y * w1, vr.z * w2, vr.w * w3 };
        *(float4*)&sre[m] = wre;
        *(float4*)&sim[m] = wim;
    } else {
#pragma unroll
        for (int i = 0; i < 4; i++) {
            int n = tid + i * 256;
            int q = reflect_idx(t * HOPSZ + n - NFFT / 2);
            float w = 0.5f - 0.5f * __cosf(6.28318530717958648f * (float)n * (1.0f / 1024.0f));
            sre[MAP(n)] = xl[q] * w;
            sim[MAP(n)] = xr[q] * w;
        }
    }

    // ---- 1024-pt complex FFT: radix-4 DIF, in-place, digit-reversed output ----
    // rounds 0..3 with register twiddles; round 4 (q=1, twiddle-free) via b128
#pragma unroll
    for (int r = 0; r < 4; r++) {
        __syncthreads();
        const int lq = 8 - 2 * r;        // q = 256,64,16,4
        const int q  = 1 << lq;
        int n = tid & (q - 1);
        int g = tid >> lq;
        int base = (g << (lq + 2)) + n;
        int i0 = MAP(base);
        int i1 = MAP(base + q);
        int i2 = MAP(base + 2 * q);
        int i3 = MAP(base + 3 * q);
        float ar = sre[i0], ai = sim[i0];
        float br = sre[i1], bi = sim[i1];
        float cr = sre[i2], ci = sim[i2];
        float dr = sre[i3], di = sim[i3];
        float t0r = ar + cr, t0i = ai + ci;
        float t1r = ar - cr, t1i = ai - ci;
        float t2r = br + dr, t2i = bi + di;
        float t3r = br - dr, t3i = bi - di;
        float u0r = t0r + t2r, u0i = t0i + t2i;
        float v2r = t0r - t2r, v2i = t0i - t2i;
        float v1r = t1r + t3i, v1i = t1i - t3r;   // t1 - i*t3
        float v3r = t1r - t3i, v3i = t1i + t3r;   // t1 + i*t3
        // register twiddles: w1 = W_1024^(n<<2r), w2 = w1^2, w3 = w1*w2
        int j1 = n << (2 * r);
        float w1s, w1c;
        __sincosf(-6.28318530717958648f * (float)j1 * (1.0f / 1024.0f), &w1s, &w1c);
        float w2c = w1c * w1c - w1s * w1s;
        float w2s = 2.0f * w1c * w1s;
        float w3c = w1c * w2c - w1s * w2s;
        float w3s = w1c * w2s + w1s * w2c;
        sre[i0] = u0r;                       sim[i0] = u0i;
        sre[i1] = v1r * w1c - v1i * w1s;     sim[i1] = v1r * w1s + v1i * w1c;
        sre[i2] = v2r * w2c - v2i * w2s;     sim[i2] = v2r * w2s + v2i * w2c;
        sre[i3] = v3r * w3c - v3i * w3s;     sim[i3] = v3r * w3s + v3i * w3c;
    }
    __syncthreads();
    {
        // round 4: q=1, W=1; 4 consecutive points per thread, b128 in/out
        int m = MAP(tid << 2);               // 4-aligned -> 16B-aligned bytes
        float4 re = *(const float4*)&sre[m];
        float4 im = *(const float4*)&sim[m];
        float t0r = re.x + re.z, t0i = im.x + im.z;
        float t1r = re.x - re.z, t1i = im.x - im.z;
        float t2r = re.y + re.w, t2i = im.y + im.w;
        float t3r = re.y - re.w, t3i = im.y - im.w;
        float4 ore, oim;
        ore.x = t0r + t2r;  oim.x = t0i + t2i;
        ore.y = t1r + t3i;  oim.y = t1i - t3r;   // t1 - i*t3
        ore.z = t0r - t2r;  oim.z = t0i - t2i;
        ore.w = t1r - t3i;  oim.w = t1i + t3r;   // t1 + i*t3
        *(float4*)&sre[m] = ore;
        *(float4*)&sim[m] = oim;
    }
    __syncthreads();

    const size_t frame_base = (size_t)(b * NFRAMES + t) * 6 * SSTR;
    auto store = [&](int c, int f, float v) {
        if (DIRECT)
            dst[(((size_t)(b * 6 + c)) * NF + f) * NFRAMES + t] = v;
        else
            dst[frame_base + (size_t)c * SSTR + f] = v;
    };

    // ---- unpack L/R spectra (digit-reversed positions), per-bin channels ----
    for (int f = tid; f < NF; f += 256) {
        int pa = MAP(digitrev4_10(f));
        int pb = MAP(digitrev4_10((NFFT - f) & (NFFT - 1)));
        float Ar = sre[pa], Ai = sim[pa];
        float Br = sre[pb], Bi = sim[pb];
        float Lre = 0.5f * (Ar + Br), Lim = 0.5f * (Ai - Bi);
        float Rre = 0.5f * (Ai + Bi), Rim = 0.5f * (Br - Ar);
        float spr = 0.5f * (Lre + Rre), spi = 0.5f * (Lim + Rim);
        float m = __builtin_amdgcn_sqrtf(spr * spr + spi * spi);   // v_sqrt_f32
        smag[f] = m;
        // 20*log10(z) = 20*log10(2) * log2(z); v_log_f32 is log2
        sdb[f]  = 6.02059991327962390f * __builtin_amdgcn_logf(m + 1e-10f);
        float ipd = fast_atan2f(Lim, Lre) - fast_atan2f(Rim, Rre);
        float le  = Lre * Lre + Lim * Lim;
        float ren = Rre * Rre + Rim * Rim;
        float pan = (le - ren) * __builtin_amdgcn_rcpf(le + ren + 1e-10f);
        store(0, f, spr);
        store(1, f, spi);
        store(3, f, ipd);
        store(4, f, pan);
    }
    __syncthreads();

    // ---- HPS downsampled arrays (jax.image.resize linear, half-pixel, clamped) ----
    for (int j = tid; j < 657; j += 256) {
        int jj, fd;
        if (j < 256)      { jj = j;       fd = 256; }
        else if (j < 427) { jj = j - 256; fd = 171; }
        else if (j < 555) { jj = j - 427; fd = 128; }
        else              { jj = j - 555; fd = 102; }
        float scale = 513.0f / (float)fd;
        float xc = ((float)jj + 0.5f) * scale - 0.5f;
        float fl = floorf(xc);
        float w  = xc - fl;
        int i0 = (int)fl;
        int c0 = min(max(i0, 0), NF - 1);
        int c1 = min(max(i0 + 1, 0), NF - 1);
        sdown[j] = (1.0f - w) * smag[c0] + w * smag[c1];
    }
    __syncthreads();

    // ---- harmonic product + psychoacoustic spreading ----
    // Gaussian taps |d|>=6 weigh <= 6.1e-9 -> truncated (abs err < 2.5e-6 on ch5)
    const float SW[21] = {
        7.6945986e-23f, 1.0279774e-18f, 5.0522711e-15f, 9.1347204e-12f,
        6.0758829e-09f, 1.4867195e-06f, 1.3383023e-04f, 4.4318484e-03f,
        5.3990967e-02f, 2.4197072e-01f, 3.9894228e-01f, 2.4197072e-01f,
        5.3990967e-02f, 4.4318484e-03f, 1.3383023e-04f, 1.4867195e-06f,
        6.0758829e-09f, 9.1347204e-12f, 5.0522711e-15f, 1.0279774e-18f,
        7.6945986e-23f };
    const int offs[4] = { 0, 256, 427, 555 };
    const int fds[4]  = { 256, 171, 128, 102 };

    for (int f = tid; f < NF; f += 256) {
        float h = smag[f];
#pragma unroll
        for (int q = 0; q < 4; q++) {
            float scale = (float)fds[q] * (1.0f / 513.0f);
            float xc = ((float)f + 0.5f) * scale - 0.5f;
            float fl = floorf(xc);
            float w  = xc - fl;
            int i0 = (int)fl;
            int c0 = min(max(i0, 0), fds[q] - 1);
            int c1 = min(max(i0 + 1, 0), fds[q] - 1);
            h *= (1.0f - w) * sdown[offs[q] + c0] + w * sdown[offs[q] + c1];
        }
        store(2, f, h);

        float acc = 0.0f;
#pragma unroll
        for (int d = -5; d <= 5; d++) {
            int ff = f + d;
            if (ff >= 0 && ff < NF) acc += SW[d + 10] * sdb[ff];
        }
        store(5, f, acc - 20.0f);
    }
}

// (b,t,c,f) staged -> (b,c,f,t) final; 64(f) x 128(t) tiles, float4 both directions
__global__ __launch_bounds__(256)
void w2t_transpose_kernel(const float* __restrict__ ws, float* __restrict__ out) {
    __shared__ float tile[64][TT + 4];   // [f_local][t_local], row stride 132 (16B-aligned)
    const int bc = blockIdx.z;           // b*6 + c
    const int b  = bc / 6;
    const int c  = bc - b * 6;
    const int f0 = blockIdx.x * 64;
    const int t0 = blockIdx.y * TT;
    const int u  = threadIdx.x;

    // load: rows = t (16 per pass, 8 passes), float4 along f
    {
        const int txq = u & 15;          // f quad index
        const int ty  = u >> 4;          // 0..15
#pragma unroll
        for (int i = 0; i < 8; i++) {
            int tl = ty + 16 * i;
            int tt = t0 + tl;
            if (tt < NFRAMES) {
                const float* row = ws + ((size_t)((size_t)b * NFRAMES + tt) * 6 + c) * SSTR + f0;
                int fb = txq * 4;
                if (f0 + fb + 3 < NF) {
                    float4 v = *(const float4*)(row + fb);
                    tile[fb + 0][tl] = v.x;
                    tile[fb + 1][tl] = v.y;
                    tile[fb + 2][tl] = v.z;
                    tile[fb + 3][tl] = v.w;
                } else {
#pragma unroll
                    for (int j = 0; j < 4; j++)
                        if (f0 + fb + j < NF) tile[fb + j][tl] = row[fb + j];
                }
            }
        }
    }
    __syncthreads();

    // store: rows = f (8 per pass, 8 passes), float4 along t (512B segments per wave-row)
    {
        const int tq = u & 31;           // t quad index
        const int fy = u >> 5;           // 0..7
#pragma unroll
        for (int i = 0; i < 8; i++) {
            int fl = fy + 8 * i;
            int ff = f0 + fl;
            if (ff < NF) {
                float* orow = out + ((size_t)bc * NF + ff) * NFRAMES + t0;
                int tb = tq * 4;
                if (t0 + tb + 3 < NFRAMES) {
                    float4 v;
                    v.x = tile[fl][tb + 0];
                    v.y = tile[fl][tb + 1];
                    v.z = tile[fl][tb + 2];
                    v.w = tile[fl][tb + 3];
                    *(float4*)(orow + tb) = v;
                } else {
#pragma unroll
                    for (int j = 0; j < 4; j++)
                        if (t0 + tb + j < NFRAMES) orow[tb + j] = tile[fl][tb + j];
                }
            }
        }
    }
}

extern "C" void kernel_launch(void* const* d_in, const int* in_sizes, int n_in,
                              void* d_out, int out_size, void* d_ws, size_t ws_size,
                              hipStream_t stream) {
    const float* x = (const float*)d_in[0];
    float* out = (float*)d_out;

    const size_t staged_bytes = (size_t)NBATCH * NFRAMES * 6 * SSTR * sizeof(float);
    dim3 g1(NBATCH * NFRAMES);

    if (ws_size >= staged_bytes) {
        float* ws = (float*)d_ws;
        hipLaunchKernelGGL((w2t_frame_kernel<0>), g1, dim3(256), 0, stream, x, ws);
        dim3 g2((NF + 63) / 64, (NFRAMES + TT - 1) / TT, NBATCH * 6);
        hipLaunchKernelGGL(w2t_transpose_kernel, g2, dim3(256), 0, stream, ws, out);
    } else {
        hipLaunchKernelGGL((w2t_frame_kernel<1>), g1, dim3(256), 0, stream, x, out);
    }
}